// Round 9
// baseline (414.311 us; speedup 1.0000x reference)
//
#include <hip/hip_runtime.h>
#include <hip/hip_bf16.h>

// KMeans predict: ids = argmin_k ||c_k||^2 - 2 x.c_k    (N=500000, D=64, K=1024)
// Pass 0: fp64 ||c||^2 table (authority for pass2 + pass1 C-init).
// Pass 1: 32x32x16 f16 MFMA, A=centers (LDS, hi only), B=points (regs, hi+lo).
//         Verified 2-barrier/stage schedule + register prefetch (R8). NEW:
//         tiles processed in PAIRS with two independent accumulator chains,
//         MFMAs interleaved -> MFMA latency (not issue) was the suspected
//         binder: per-tile 8 serially-dependent MFMAs + fold left the matrix
//         pipe idle between dependent issues at every occupancy tested
//         (38-64%, perf invariant). Per-tile MFMA sequence is bit-identical,
//         so results are unchanged (absmax 0 preserved).
// Pass 2: fp64-exact wave-per-point rescan of uncertain points (unchanged).

#define N_PTS 500000
#define DIM   64
#define K_CENT 1024
#define MARGIN 8.0e-3f   // covers c-hi noise (~2e-3 rms) + 4-bit pack quant

typedef _Float16 half8   __attribute__((ext_vector_type(8)));
typedef float    floatx16 __attribute__((ext_vector_type(16)));

// ---------------------------------------------------------------- pass 0 ----
// fp64 ||c||^2 table, 1024 centers, one thread each.
__global__ void kmeans_m2pre(const float* __restrict__ centers,
                             double* __restrict__ m2d)
{
    const int c = blockIdx.x * 256 + threadIdx.x;
    if (c >= K_CENT) return;
    const float4* crow = (const float4*)(centers + (size_t)c * DIM);
    double s = 0.0;
    #pragma unroll
    for (int kc = 0; kc < 16; ++kc) {
        float4 v = crow[kc];
        double a = v.x, b = v.y, cc = v.z, d = v.w;
        s += a * a + b * b + cc * cc + d * d;
    }
    m2d[c] = s;
}

// ---------------------------------------------------------------- pass 1 ----
// 512 threads = 8 waves; each wave owns 32 points (one 32-col C tile).
// Centers staged fp16(hi) to LDS in 4 stages of 256, row stride 72 halves
// (144 B — conflict-free). negm2p holds -0.5||c||^2 fp32 permuted into MFMA
// C-fragment order [tile][h][reg] so the acc loads as one broadcast floatx16.
// Stage s+1's global loads are issued during stage s's compute (reg prefetch).
__launch_bounds__(512, 3)
__global__ void kmeans_pass1(const float* __restrict__ x,
                             const float* __restrict__ centers,
                             const double* __restrict__ m2d,
                             int* __restrict__ out,
                             int* __restrict__ counter,
                             int* __restrict__ ulist,
                             int capacity)
{
    __shared__ __align__(16) _Float16 ldsC[256 * 72];   // 36.9 KB
    __shared__ __align__(64) float negm2p[256];         // [8 tiles][2 h][16 regs]

    const int tid  = threadIdx.x;
    const int lane = tid & 63;
    const int wave = tid >> 6;
    const int col  = lane & 31;      // point within wave's 32
    const int h    = lane >> 5;      // k-half selector (8 of 16 per chunk)

    const int p  = blockIdx.x * 256 + wave * 32 + col;
    const int pc = p > N_PTS - 1 ? N_PTS - 1 : p;       // tail clamp (dup)

    // staging role: thread t -> center c = t>>1 of the stage, half hh = t&1
    const int cst = tid >> 1, hh = tid & 1;

    // ---- B fragments (points), hi+lo: B[k = c*16 + h*8 + j][n = col] ----
    half8 bh[4], bl[4];
    {
        const float* xr = x + (size_t)pc * DIM + h * 8;
        #pragma unroll
        for (int c = 0; c < 4; ++c) {
            float4 f0 = *(const float4*)(xr + c * 16);
            float4 f1 = *(const float4*)(xr + c * 16 + 4);
            float v[8] = {f0.x, f0.y, f0.z, f0.w, f1.x, f1.y, f1.z, f1.w};
            half8 hi, lo;
            #pragma unroll
            for (int j = 0; j < 8; ++j) {
                _Float16 hj = (_Float16)v[j];
                hi[j] = hj;
                lo[j] = (_Float16)(v[j] - (float)hj);   // exact residual
            }
            bh[c] = hi; bl[c] = lo;
        }
    }

    // ---- prefetch stage 0 into registers (8 x float4 = 32 floats) ----
    float4 pf[8];
    {
        const float* src = centers + (size_t)cst * DIM + hh * 32;
        #pragma unroll
        for (int g = 0; g < 4; ++g) {
            pf[2 * g]     = *(const float4*)(src + g * 8);
            pf[2 * g + 1] = *(const float4*)(src + g * 8 + 4);
        }
    }

    float m1 = -3.0e38f, m2 = -3.0e38f;
    int   ctb = 0;

    for (int s = 0; s < 4; ++s) {
        __syncthreads();                                 // prev-stage readers
        // ---- staging: convert prefetched regs -> LDS (no global latency) ----
        {
            #pragma unroll
            for (int g = 0; g < 4; ++g) {
                float4 f0 = pf[2 * g], f1 = pf[2 * g + 1];
                float v[8] = {f0.x, f0.y, f0.z, f0.w, f1.x, f1.y, f1.z, f1.w};
                half8 hi;
                #pragma unroll
                for (int j = 0; j < 8; ++j) hi[j] = (_Float16)v[j];
                *(half8*)&ldsC[cst * 72 + hh * 32 + g * 8] = hi;
            }
            // permuted C-init table: center row r of tile ctl sits at
            // [ctl][h=(r>>2)&1][reg=(r&3)|((r>>3)<<2)]  (row=(reg&3)+8*(reg>>2)+4h)
            if (tid < 256) {
                const int r = tid & 31, ctl = tid >> 5;
                const int hp = (r >> 2) & 1, reg = (r & 3) | ((r >> 3) << 2);
                negm2p[ctl * 32 + hp * 16 + reg] =
                    -0.5f * (float)m2d[s * 256 + tid];
            }
        }
        __syncthreads();

        // ---- issue NEXT stage's global loads early (hidden under compute) ----
        if (s < 3) {
            const float* src = centers + (size_t)((s + 1) * 256 + cst) * DIM + hh * 32;
            #pragma unroll
            for (int g = 0; g < 4; ++g) {
                pf[2 * g]     = *(const float4*)(src + g * 8);
                pf[2 * g + 1] = *(const float4*)(src + g * 8 + 4);
            }
        }

        // ---- 8 center-tiles of 32, processed in PAIRS (2 indep acc chains) --
        for (int ctl = 0; ctl < 8; ctl += 2) {
            const int ct0 = s * 8 + ctl, ct1 = ct0 + 1;
            // C-init: broadcast 64B LDS loads, already in fragment order
            floatx16 acc0 = *(const floatx16*)&negm2p[ctl * 32 + h * 16];
            floatx16 acc1 = *(const floatx16*)&negm2p[(ctl + 1) * 32 + h * 16];

            // A fragments: A[m = tile*32+col][k = c*16 + h*8 + j]
            const _Float16* ap0 = &ldsC[((ctl    ) * 32 + col) * 72 + h * 8];
            const _Float16* ap1 = &ldsC[((ctl + 1) * 32 + col) * 72 + h * 8];
            #pragma unroll
            for (int c = 0; c < 4; ++c) {
                half8 a0 = *(const half8*)(ap0 + c * 16);
                half8 a1 = *(const half8*)(ap1 + c * 16);
                acc0 = __builtin_amdgcn_mfma_f32_32x32x16_f16(a0, bh[c], acc0, 0, 0, 0);
                acc1 = __builtin_amdgcn_mfma_f32_32x32x16_f16(a1, bh[c], acc1, 0, 0, 0);
                acc0 = __builtin_amdgcn_mfma_f32_32x32x16_f16(a0, bl[c], acc0, 0, 0, 0);
                acc1 = __builtin_amdgcn_mfma_f32_32x32x16_f16(a1, bl[c], acc1, 0, 0, 0);
            }

            // ---- top-2 fold: max/min per element, reg-id in low 4 bits ----
            // invariant m1 >= m2; m2' = max(m2, min(m1,k)); m1' = max(m1,k)
            const float pre0 = m1;
            #pragma unroll
            for (int i = 0; i < 16; ++i) {
                unsigned u = (__float_as_uint(acc0[i]) & 0xFFFFFFF0u) | (unsigned)i;
                float k = __uint_as_float(u);
                m2 = fmaxf(m2, fminf(m1, k));
                m1 = fmaxf(m1, k);
            }
            ctb = (m1 > pre0) ? ct0 : ctb;

            const float pre1 = m1;
            #pragma unroll
            for (int i = 0; i < 16; ++i) {
                unsigned u = (__float_as_uint(acc1[i]) & 0xFFFFFFF0u) | (unsigned)i;
                float k = __uint_as_float(u);
                m2 = fmaxf(m2, fminf(m1, k));
                m1 = fmaxf(m1, k);
            }
            ctb = (m1 > pre1) ? ct1 : ctb;
        }
    }

    // ---- epilogue: recover center id, merge the two k-halves, write ----
    {
        unsigned u = __float_as_uint(m1);
        int reg = (int)(u & 15u);
        int row = (reg & 3) + 8 * (reg >> 2) + 4 * h;
        int cid = ctb * 32 + row;

        float o1 = __shfl_xor(m1, 32);
        float o2 = __shfl_xor(m2, 32);
        int  ocid = __shfl_xor(cid, 32);
        float nm2 = fmaxf(fmaxf(m2, o2), fminf(m1, o1));
        bool take = o1 > m1;
        float nm1 = take ? o1 : m1;
        int  ncid = take ? ocid : cid;

        if (h == 0 && p < N_PTS) {
            out[p] = ncid;
            if (nm1 - nm2 < MARGIN) {                    // too close -> fp64
                int slot = atomicAdd(counter, 1);
                if (slot < capacity) ulist[slot] = p;
            }
        }
    }
}

// ---------------------------------------------------------------- pass 2 ----
// fp64-exact, ONE WAVE PER POINT. Lane q=lane&15 owns one float4 of the dim
// axis; rg=lane>>4 one of 4 rows per load -> each wave-load is a coalesced
// 1 KB read of 4 center rows. dot reduced by shfl_xor butterfly over q bits.
// ||c||^2 comes from the fp64 precompute table.
__launch_bounds__(256)
__global__ void kmeans_pass2(const float* __restrict__ x,
                             const float* __restrict__ centers,
                             const double* __restrict__ m2d,
                             int* __restrict__ out,
                             const int* __restrict__ counter,
                             const int* __restrict__ ulist,
                             int capacity)
{
    int count = *counter;
    if (count > capacity) count = capacity;

    const int tid   = threadIdx.x;
    const int lane  = tid & 63;
    const int q     = lane & 15;                 // float4 chunk of the row
    const int rg    = lane >> 4;                 // row-in-group 0..3
    const int waveg = (blockIdx.x * 256 + tid) >> 6;   // global wave id
    const int nwave = (gridDim.x * 256) >> 6;

    for (int u = waveg; u < count; u += nwave) {
        const int p = ulist[u];
        float4 xv = *(const float4*)(x + (size_t)p * DIM + q * 4);
        const double x0 = xv.x, x1 = xv.y, x2 = xv.z, x3 = xv.w;

        double bv = 1.0e300; int bi = 0;
        #pragma unroll 4
        for (int g = 0; g < 256; ++g) {
            const int row = g * 4 + rg;
            float4 cv = *(const float4*)(centers + (size_t)row * DIM + q * 4);
            double dot = (double)cv.x * x0 + (double)cv.y * x1
                       + (double)cv.z * x2 + (double)cv.w * x3;
            #pragma unroll
            for (int m = 1; m <= 8; m <<= 1)
                dot += __shfl_xor(dot, m);       // all 16 q-lanes get the total
            double s = m2d[row] - 2.0 * dot;
            if (s < bv || (s == bv && row < bi)) { bv = s; bi = row; }
        }
        #pragma unroll
        for (int m = 16; m <= 32; m <<= 1) {     // merge the 4 rg groups
            double ov = __shfl_xor(bv, m);
            int    oi = __shfl_xor(bi, m);
            if (ov < bv || (ov == bv && oi < bi)) { bv = ov; bi = oi; }
        }
        if (lane == 0) out[p] = bi;
    }
}

extern "C" void kernel_launch(void* const* d_in, const int* in_sizes, int n_in,
                              void* d_out, int out_size, void* d_ws, size_t ws_size,
                              hipStream_t stream)
{
    const float* x       = (const float*)d_in[0];
    const float* centers = (const float*)d_in[1];
    int*    out     = (int*)d_out;
    int*    counter = (int*)d_ws;
    double* m2d     = (double*)((char*)d_ws + 1024);
    int*    ulist   = (int*)((char*)d_ws + 1024 + 8192);
    int capacity = (int)((ws_size > 9216 + 64 ? ws_size - 9216 : 0) / sizeof(int));
    if (capacity > N_PTS) capacity = N_PTS;

    hipMemsetAsync(d_ws, 0, 64, stream);
    kmeans_m2pre<<<4, 256, 0, stream>>>(centers, m2d);
    dim3 g1((N_PTS + 255) / 256);     // 1954 blocks x 512 threads, 256 pts each
    kmeans_pass1<<<g1, 512, 0, stream>>>(x, centers, m2d, out, counter, ulist, capacity);
    kmeans_pass2<<<1024, 256, 0, stream>>>(x, centers, m2d, out, counter, ulist, capacity);
}

// Round 10
// 369.427 us; speedup vs baseline: 1.1215x; 1.1215x over previous
//
#include <hip/hip_runtime.h>
#include <hip/hip_bf16.h>

// KMeans predict: ids = argmin_k ||c_k||^2 - 2 x.c_k    (N=500000, D=64, K=1024)
// Pass 0: fp64 ||c||^2 table (authority for pass2 + pass1 C-init).
// Pass 1: 32x32x16 f16 MFMA, A=centers f16-hi (LDS), B=points f16-hi (regs).
//         FOUR MFMAs per tile (K=64). Score error = 2(c_lo.x + c.x_lo),
//         rms ~5.4e-3; MARGIN 1.5e-2 keeps the SNR better than the verified
//         hi+lo config (err 3.8e-3 vs margin 8e-3, absmax 0 across 4 runs).
//         R1 showed pass1 time ~linear in MFMA count (8->12 was +30%), so
//         8->4 should cut the serial MFMA chain per tile in half.
//         2-barrier/stage schedule + register prefetch (R8, verified).
// Pass 2: fp64-exact wave-per-point rescan of uncertain points (unchanged;
//         ~2x more points flagged, still small).

#define N_PTS 500000
#define DIM   64
#define K_CENT 1024
#define MARGIN 1.5e-2f   // covers c_lo.x + c.x_lo noise (~5.4e-3 rms) + pack quant

typedef _Float16 half8   __attribute__((ext_vector_type(8)));
typedef float    floatx16 __attribute__((ext_vector_type(16)));

// ---------------------------------------------------------------- pass 0 ----
// fp64 ||c||^2 table, 1024 centers, one thread each.
__global__ void kmeans_m2pre(const float* __restrict__ centers,
                             double* __restrict__ m2d)
{
    const int c = blockIdx.x * 256 + threadIdx.x;
    if (c >= K_CENT) return;
    const float4* crow = (const float4*)(centers + (size_t)c * DIM);
    double s = 0.0;
    #pragma unroll
    for (int kc = 0; kc < 16; ++kc) {
        float4 v = crow[kc];
        double a = v.x, b = v.y, cc = v.z, d = v.w;
        s += a * a + b * b + cc * cc + d * d;
    }
    m2d[c] = s;
}

// ---------------------------------------------------------------- pass 1 ----
// 512 threads = 8 waves; each wave owns 32 points (one 32-col C tile).
// Centers staged fp16(hi) to LDS in 4 stages of 256, row stride 72 halves
// (144 B — conflict-free). negm2p holds -0.5||c||^2 fp32 permuted into MFMA
// C-fragment order [tile][h][reg] so the acc loads as one broadcast floatx16.
// Stage s+1's global loads are issued during stage s's compute (reg prefetch).
__launch_bounds__(512, 4)
__global__ void kmeans_pass1(const float* __restrict__ x,
                             const float* __restrict__ centers,
                             const double* __restrict__ m2d,
                             int* __restrict__ out,
                             int* __restrict__ counter,
                             int* __restrict__ ulist,
                             int capacity)
{
    __shared__ __align__(16) _Float16 ldsC[256 * 72];   // 36.9 KB
    __shared__ __align__(64) float negm2p[256];         // [8 tiles][2 h][16 regs]

    const int tid  = threadIdx.x;
    const int lane = tid & 63;
    const int wave = tid >> 6;
    const int col  = lane & 31;      // point within wave's 32
    const int h    = lane >> 5;      // k-half selector (8 of 16 per chunk)

    const int p  = blockIdx.x * 256 + wave * 32 + col;
    const int pc = p > N_PTS - 1 ? N_PTS - 1 : p;       // tail clamp (dup)

    // staging role: thread t -> center c = t>>1 of the stage, half hh = t&1
    const int cst = tid >> 1, hh = tid & 1;

    // ---- B fragments (points), hi only: B[k = c*16 + h*8 + j][n = col] ----
    half8 bh[4];
    {
        const float* xr = x + (size_t)pc * DIM + h * 8;
        #pragma unroll
        for (int c = 0; c < 4; ++c) {
            float4 f0 = *(const float4*)(xr + c * 16);
            float4 f1 = *(const float4*)(xr + c * 16 + 4);
            float v[8] = {f0.x, f0.y, f0.z, f0.w, f1.x, f1.y, f1.z, f1.w};
            half8 hi;
            #pragma unroll
            for (int j = 0; j < 8; ++j) hi[j] = (_Float16)v[j];
            bh[c] = hi;
        }
    }

    // ---- prefetch stage 0 into registers (8 x float4 = 32 floats) ----
    float4 pf[8];
    {
        const float* src = centers + (size_t)cst * DIM + hh * 32;
        #pragma unroll
        for (int g = 0; g < 4; ++g) {
            pf[2 * g]     = *(const float4*)(src + g * 8);
            pf[2 * g + 1] = *(const float4*)(src + g * 8 + 4);
        }
    }

    float m1 = -3.0e38f, m2 = -3.0e38f;
    int   ctb = 0;

    for (int s = 0; s < 4; ++s) {
        __syncthreads();                                 // prev-stage readers
        // ---- staging: convert prefetched regs -> LDS (no global latency) ----
        {
            #pragma unroll
            for (int g = 0; g < 4; ++g) {
                float4 f0 = pf[2 * g], f1 = pf[2 * g + 1];
                float v[8] = {f0.x, f0.y, f0.z, f0.w, f1.x, f1.y, f1.z, f1.w};
                half8 hi;
                #pragma unroll
                for (int j = 0; j < 8; ++j) hi[j] = (_Float16)v[j];
                *(half8*)&ldsC[cst * 72 + hh * 32 + g * 8] = hi;
            }
            // permuted C-init table: center row r of tile ctl sits at
            // [ctl][h=(r>>2)&1][reg=(r&3)|((r>>3)<<2)]  (row=(reg&3)+8*(reg>>2)+4h)
            if (tid < 256) {
                const int r = tid & 31, ctl = tid >> 5;
                const int hp = (r >> 2) & 1, reg = (r & 3) | ((r >> 3) << 2);
                negm2p[ctl * 32 + hp * 16 + reg] =
                    -0.5f * (float)m2d[s * 256 + tid];
            }
        }
        __syncthreads();

        // ---- issue NEXT stage's global loads early (hidden under compute) ----
        if (s < 3) {
            const float* src = centers + (size_t)((s + 1) * 256 + cst) * DIM + hh * 32;
            #pragma unroll
            for (int g = 0; g < 4; ++g) {
                pf[2 * g]     = *(const float4*)(src + g * 8);
                pf[2 * g + 1] = *(const float4*)(src + g * 8 + 4);
            }
        }

        // ---- 8 center-tiles of 32 in this stage ----
        for (int ctl = 0; ctl < 8; ++ctl) {
            const int ct = s * 8 + ctl;
            // C-init: one broadcast 64B LDS load, already in fragment order
            floatx16 acc = *(const floatx16*)&negm2p[ctl * 32 + h * 16];

            // A fragments (centers): A[m = ctl*32+col][k = c*16 + h*8 + j]
            const _Float16* ap = &ldsC[(ctl * 32 + col) * 72 + h * 8];
            #pragma unroll
            for (int c = 0; c < 4; ++c) {
                half8 a = *(const half8*)(ap + c * 16);
                acc = __builtin_amdgcn_mfma_f32_32x32x16_f16(a, bh[c], acc, 0, 0, 0);
            }

            // ---- top-2 fold: max/min per element, reg-id in low 4 bits ----
            // invariant m1 >= m2; m2' = max(m2, min(m1,k)); m1' = max(m1,k)
            const float pre = m1;
            #pragma unroll
            for (int i = 0; i < 16; ++i) {
                unsigned u = (__float_as_uint(acc[i]) & 0xFFFFFFF0u) | (unsigned)i;
                float k = __uint_as_float(u);
                m2 = fmaxf(m2, fminf(m1, k));
                m1 = fmaxf(m1, k);
            }
            ctb = (m1 > pre) ? ct : ctb;
        }
    }

    // ---- epilogue: recover center id, merge the two k-halves, write ----
    {
        unsigned u = __float_as_uint(m1);
        int reg = (int)(u & 15u);
        int row = (reg & 3) + 8 * (reg >> 2) + 4 * h;
        int cid = ctb * 32 + row;

        float o1 = __shfl_xor(m1, 32);
        float o2 = __shfl_xor(m2, 32);
        int  ocid = __shfl_xor(cid, 32);
        float nm2 = fmaxf(fmaxf(m2, o2), fminf(m1, o1));
        bool take = o1 > m1;
        float nm1 = take ? o1 : m1;
        int  ncid = take ? ocid : cid;

        if (h == 0 && p < N_PTS) {
            out[p] = ncid;
            if (nm1 - nm2 < MARGIN) {                    // too close -> fp64
                int slot = atomicAdd(counter, 1);
                if (slot < capacity) ulist[slot] = p;
            }
        }
    }
}

// ---------------------------------------------------------------- pass 2 ----
// fp64-exact, ONE WAVE PER POINT. Lane q=lane&15 owns one float4 of the dim
// axis; rg=lane>>4 one of 4 rows per load -> each wave-load is a coalesced
// 1 KB read of 4 center rows. dot reduced by shfl_xor butterfly over q bits.
// ||c||^2 comes from the fp64 precompute table.
__launch_bounds__(256)
__global__ void kmeans_pass2(const float* __restrict__ x,
                             const float* __restrict__ centers,
                             const double* __restrict__ m2d,
                             int* __restrict__ out,
                             const int* __restrict__ counter,
                             const int* __restrict__ ulist,
                             int capacity)
{
    int count = *counter;
    if (count > capacity) count = capacity;

    const int tid   = threadIdx.x;
    const int lane  = tid & 63;
    const int q     = lane & 15;                 // float4 chunk of the row
    const int rg    = lane >> 4;                 // row-in-group 0..3
    const int waveg = (blockIdx.x * 256 + tid) >> 6;   // global wave id
    const int nwave = (gridDim.x * 256) >> 6;

    for (int u = waveg; u < count; u += nwave) {
        const int p = ulist[u];
        float4 xv = *(const float4*)(x + (size_t)p * DIM + q * 4);
        const double x0 = xv.x, x1 = xv.y, x2 = xv.z, x3 = xv.w;

        double bv = 1.0e300; int bi = 0;
        #pragma unroll 4
        for (int g = 0; g < 256; ++g) {
            const int row = g * 4 + rg;
            float4 cv = *(const float4*)(centers + (size_t)row * DIM + q * 4);
            double dot = (double)cv.x * x0 + (double)cv.y * x1
                       + (double)cv.z * x2 + (double)cv.w * x3;
            #pragma unroll
            for (int m = 1; m <= 8; m <<= 1)
                dot += __shfl_xor(dot, m);       // all 16 q-lanes get the total
            double s = m2d[row] - 2.0 * dot;
            if (s < bv || (s == bv && row < bi)) { bv = s; bi = row; }
        }
        #pragma unroll
        for (int m = 16; m <= 32; m <<= 1) {     // merge the 4 rg groups
            double ov = __shfl_xor(bv, m);
            int    oi = __shfl_xor(bi, m);
            if (ov < bv || (ov == bv && oi < bi)) { bv = ov; bi = oi; }
        }
        if (lane == 0) out[p] = bi;
    }
}

extern "C" void kernel_launch(void* const* d_in, const int* in_sizes, int n_in,
                              void* d_out, int out_size, void* d_ws, size_t ws_size,
                              hipStream_t stream)
{
    const float* x       = (const float*)d_in[0];
    const float* centers = (const float*)d_in[1];
    int*    out     = (int*)d_out;
    int*    counter = (int*)d_ws;
    double* m2d     = (double*)((char*)d_ws + 1024);
    int*    ulist   = (int*)((char*)d_ws + 1024 + 8192);
    int capacity = (int)((ws_size > 9216 + 64 ? ws_size - 9216 : 0) / sizeof(int));
    if (capacity > N_PTS) capacity = N_PTS;

    hipMemsetAsync(d_ws, 0, 64, stream);
    kmeans_m2pre<<<4, 256, 0, stream>>>(centers, m2d);
    dim3 g1((N_PTS + 255) / 256);     // 1954 blocks x 512 threads, 256 pts each
    kmeans_pass1<<<g1, 512, 0, stream>>>(x, centers, m2d, out, counter, ulist, capacity);
    kmeans_pass2<<<1024, 256, 0, stream>>>(x, centers, m2d, out, counter, ulist, capacity);
}

// Round 11
// 362.065 us; speedup vs baseline: 1.1443x; 1.0203x over previous
//
#include <hip/hip_runtime.h>
#include <hip/hip_bf16.h>

// KMeans predict: ids = argmin_k ||c_k||^2 - 2 x.c_k    (N=500000, D=64, K=1024)
// Pass 0: fp64 ||c||^2 table (authority for pass2 + pass1 C-init).
// Pass 1: 32x32x16 f16 MFMA, A=centers f16-hi (LDS), B=points f16-hi (regs).
//         4 MFMAs/tile (K=64). MARGIN 1.5e-2 covers f16-hi score noise
//         (~5.4e-3 rms; verified absmax 0 in R10). TWO stages x 512 centers
//         (LDS 75.8 KB, 2 blocks/CU): halves barrier count vs 4-stage.
//         No reg-prefetch (R8 proved it neutral; saves 20 VGPR).
//         Cost model (R1/R4/R10): pass1 = ~124us base + 6.9us/MFMA-per-tile.
// Pass 2: fp64-exact wave-per-point rescan; grid 3072 (was 1024) since the
//         1.5e-2 margin flags ~50k points (~30us at grid 1024).

#define N_PTS 500000
#define DIM   64
#define K_CENT 1024
#define MARGIN 1.5e-2f   // covers f16-hi product noise (~5.4e-3 rms) + pack quant

typedef _Float16 half8   __attribute__((ext_vector_type(8)));
typedef float    floatx16 __attribute__((ext_vector_type(16)));

// ---------------------------------------------------------------- pass 0 ----
// fp64 ||c||^2 table, 1024 centers, one thread each.
__global__ void kmeans_m2pre(const float* __restrict__ centers,
                             double* __restrict__ m2d)
{
    const int c = blockIdx.x * 256 + threadIdx.x;
    if (c >= K_CENT) return;
    const float4* crow = (const float4*)(centers + (size_t)c * DIM);
    double s = 0.0;
    #pragma unroll
    for (int kc = 0; kc < 16; ++kc) {
        float4 v = crow[kc];
        double a = v.x, b = v.y, cc = v.z, d = v.w;
        s += a * a + b * b + cc * cc + d * d;
    }
    m2d[c] = s;
}

// ---------------------------------------------------------------- pass 1 ----
// 512 threads = 8 waves; each wave owns 32 points (one 32-col C tile).
// Centers staged fp16(hi) to LDS in 2 stages of 512, row stride 72 halves
// (144 B — conflict-free). negm2p holds -0.5||c||^2 fp32 permuted into MFMA
// C-fragment order [tile][h][reg] so the acc loads as one broadcast floatx16.
__launch_bounds__(512, 4)
__global__ void kmeans_pass1(const float* __restrict__ x,
                             const float* __restrict__ centers,
                             const double* __restrict__ m2d,
                             int* __restrict__ out,
                             int* __restrict__ counter,
                             int* __restrict__ ulist,
                             int capacity)
{
    __shared__ __align__(16) _Float16 ldsC[512 * 72];   // 73.7 KB
    __shared__ __align__(64) float negm2p[512];         // [16 tiles][2 h][16 regs]

    const int tid  = threadIdx.x;
    const int lane = tid & 63;
    const int wave = tid >> 6;
    const int col  = lane & 31;      // point within wave's 32
    const int h    = lane >> 5;      // k-half selector (8 of 16 per chunk)

    const int p  = blockIdx.x * 256 + wave * 32 + col;
    const int pc = p > N_PTS - 1 ? N_PTS - 1 : p;       // tail clamp (dup)

    // ---- B fragments (points), hi only: B[k = c*16 + h*8 + j][n = col] ----
    half8 bh[4];
    {
        const float* xr = x + (size_t)pc * DIM + h * 8;
        #pragma unroll
        for (int c = 0; c < 4; ++c) {
            float4 f0 = *(const float4*)(xr + c * 16);
            float4 f1 = *(const float4*)(xr + c * 16 + 4);
            float v[8] = {f0.x, f0.y, f0.z, f0.w, f1.x, f1.y, f1.z, f1.w};
            half8 hi;
            #pragma unroll
            for (int j = 0; j < 8; ++j) hi[j] = (_Float16)v[j];
            bh[c] = hi;
        }
    }

    float m1 = -3.0e38f, m2 = -3.0e38f;
    int   ctb = 0;

    for (int s = 0; s < 2; ++s) {
        __syncthreads();                                 // prev-stage readers
        // ---- stage 512 centers: 8 iters, thread t -> center (t>>3)+it*64,
        //      eighth t&7 (8-lane groups read 256B contiguous -> coalesced) ----
        {
            const int ch = tid & 7;
            #pragma unroll
            for (int it = 0; it < 8; ++it) {
                const int c = (tid >> 3) + it * 64;
                const float* src = centers + (size_t)(s * 512 + c) * DIM + ch * 8;
                float4 f0 = *(const float4*)(src);
                float4 f1 = *(const float4*)(src + 4);
                float v[8] = {f0.x, f0.y, f0.z, f0.w, f1.x, f1.y, f1.z, f1.w};
                half8 hi;
                #pragma unroll
                for (int j = 0; j < 8; ++j) hi[j] = (_Float16)v[j];
                *(half8*)&ldsC[c * 72 + ch * 8] = hi;
            }
            // permuted C-init table: center row r of tile ctl sits at
            // [ctl][h=(r>>2)&1][reg=(r&3)|((r>>3)<<2)]  (row=(reg&3)+8*(reg>>2)+4h)
            {
                const int r = tid & 31, ctl = tid >> 5;   // ctl 0..15
                const int hp = (r >> 2) & 1, reg = (r & 3) | ((r >> 3) << 2);
                negm2p[ctl * 32 + hp * 16 + reg] =
                    -0.5f * (float)m2d[s * 512 + tid];
            }
        }
        __syncthreads();

        // ---- 16 center-tiles of 32 in this stage ----
        for (int ctl = 0; ctl < 16; ++ctl) {
            const int ct = s * 16 + ctl;
            // C-init: one broadcast 64B LDS load, already in fragment order
            floatx16 acc = *(const floatx16*)&negm2p[ctl * 32 + h * 16];

            // A fragments (centers): A[m = ctl*32+col][k = c*16 + h*8 + j]
            const _Float16* ap = &ldsC[(ctl * 32 + col) * 72 + h * 8];
            #pragma unroll
            for (int c = 0; c < 4; ++c) {
                half8 a = *(const half8*)(ap + c * 16);
                acc = __builtin_amdgcn_mfma_f32_32x32x16_f16(a, bh[c], acc, 0, 0, 0);
            }

            // ---- top-2 fold: max/min per element, reg-id in low 4 bits ----
            // invariant m1 >= m2; m2' = max(m2, min(m1,k)); m1' = max(m1,k)
            const float pre = m1;
            #pragma unroll
            for (int i = 0; i < 16; ++i) {
                unsigned u = (__float_as_uint(acc[i]) & 0xFFFFFFF0u) | (unsigned)i;
                float k = __uint_as_float(u);
                m2 = fmaxf(m2, fminf(m1, k));
                m1 = fmaxf(m1, k);
            }
            ctb = (m1 > pre) ? ct : ctb;
        }
    }

    // ---- epilogue: recover center id, merge the two k-halves, write ----
    {
        unsigned u = __float_as_uint(m1);
        int reg = (int)(u & 15u);
        int row = (reg & 3) + 8 * (reg >> 2) + 4 * h;
        int cid = ctb * 32 + row;

        float o1 = __shfl_xor(m1, 32);
        float o2 = __shfl_xor(m2, 32);
        int  ocid = __shfl_xor(cid, 32);
        float nm2 = fmaxf(fmaxf(m2, o2), fminf(m1, o1));
        bool take = o1 > m1;
        float nm1 = take ? o1 : m1;
        int  ncid = take ? ocid : cid;

        if (h == 0 && p < N_PTS) {
            out[p] = ncid;
            if (nm1 - nm2 < MARGIN) {                    // too close -> fp64
                int slot = atomicAdd(counter, 1);
                if (slot < capacity) ulist[slot] = p;
            }
        }
    }
}

// ---------------------------------------------------------------- pass 2 ----
// fp64-exact, ONE WAVE PER POINT. Lane q=lane&15 owns one float4 of the dim
// axis; rg=lane>>4 one of 4 rows per load -> each wave-load is a coalesced
// 1 KB read of 4 center rows. dot reduced by shfl_xor butterfly over q bits.
// ||c||^2 comes from the fp64 precompute table.
__launch_bounds__(256)
__global__ void kmeans_pass2(const float* __restrict__ x,
                             const float* __restrict__ centers,
                             const double* __restrict__ m2d,
                             int* __restrict__ out,
                             const int* __restrict__ counter,
                             const int* __restrict__ ulist,
                             int capacity)
{
    int count = *counter;
    if (count > capacity) count = capacity;

    const int tid   = threadIdx.x;
    const int lane  = tid & 63;
    const int q     = lane & 15;                 // float4 chunk of the row
    const int rg    = lane >> 4;                 // row-in-group 0..3
    const int waveg = (blockIdx.x * 256 + tid) >> 6;   // global wave id
    const int nwave = (gridDim.x * 256) >> 6;

    for (int u = waveg; u < count; u += nwave) {
        const int p = ulist[u];
        float4 xv = *(const float4*)(x + (size_t)p * DIM + q * 4);
        const double x0 = xv.x, x1 = xv.y, x2 = xv.z, x3 = xv.w;

        double bv = 1.0e300; int bi = 0;
        #pragma unroll 4
        for (int g = 0; g < 256; ++g) {
            const int row = g * 4 + rg;
            float4 cv = *(const float4*)(centers + (size_t)row * DIM + q * 4);
            double dot = (double)cv.x * x0 + (double)cv.y * x1
                       + (double)cv.z * x2 + (double)cv.w * x3;
            #pragma unroll
            for (int m = 1; m <= 8; m <<= 1)
                dot += __shfl_xor(dot, m);       // all 16 q-lanes get the total
            double s = m2d[row] - 2.0 * dot;
            if (s < bv || (s == bv && row < bi)) { bv = s; bi = row; }
        }
        #pragma unroll
        for (int m = 16; m <= 32; m <<= 1) {     // merge the 4 rg groups
            double ov = __shfl_xor(bv, m);
            int    oi = __shfl_xor(bi, m);
            if (ov < bv || (ov == bv && oi < bi)) { bv = ov; bi = oi; }
        }
        if (lane == 0) out[p] = bi;
    }
}

extern "C" void kernel_launch(void* const* d_in, const int* in_sizes, int n_in,
                              void* d_out, int out_size, void* d_ws, size_t ws_size,
                              hipStream_t stream)
{
    const float* x       = (const float*)d_in[0];
    const float* centers = (const float*)d_in[1];
    int*    out     = (int*)d_out;
    int*    counter = (int*)d_ws;
    double* m2d     = (double*)((char*)d_ws + 1024);
    int*    ulist   = (int*)((char*)d_ws + 1024 + 8192);
    int capacity = (int)((ws_size > 9216 + 64 ? ws_size - 9216 : 0) / sizeof(int));
    if (capacity > N_PTS) capacity = N_PTS;

    hipMemsetAsync(d_ws, 0, 64, stream);
    kmeans_m2pre<<<4, 256, 0, stream>>>(centers, m2d);
    dim3 g1((N_PTS + 255) / 256);     // 1954 blocks x 512 threads, 256 pts each
    kmeans_pass1<<<g1, 512, 0, stream>>>(x, centers, m2d, out, counter, ulist, capacity);
    kmeans_pass2<<<3072, 256, 0, stream>>>(x, centers, m2d, out, counter, ulist, capacity);
}